// Round 4
// baseline (21.778 us; speedup 1.0000x reference)
//
#include <hip/hip_runtime.h>

#define LEN   16384
#define NB    128
#define NTAPS 128
#define LOUT  16513          // LEN + 2*128 - 128 + 1
#define SPAN  16800          // staged xp floats (full row + B-read overhang + pad)
#define SPAN4 (SPAN/4)       // 4200

typedef __attribute__((ext_vector_type(8))) short bf16x8;
typedef __attribute__((ext_vector_type(4))) float f32x4;

__device__ __forceinline__ unsigned short f2bf(float f) {
    union { float f; unsigned u; } c; c.f = f;
    unsigned r = c.u + 0x7FFF + ((c.u >> 16) & 1);   // RNE
    return (unsigned short)(r >> 16);
}

__global__ __launch_bounds__(1024) void fused_fir(
    const float* __restrict__ x, const float* __restrict__ conv_w,
    const float* __restrict__ conv_b, const float* __restrict__ fc_w,
    const float* __restrict__ fc_b, float* __restrict__ out)
{
    const int b   = blockIdx.x;
    const int tid = threadIdx.x;

    __shared__ unsigned short sxp[SPAN]; // full-row xp, bf16; sxp[i]=x[i-128] zero-padded
    __shared__ unsigned short fp[288];   // padded shifted filter; fp[j]=filt[j-128]
    __shared__ float scw[384];           // conv_w
    __shared__ float scb[128];           // conv_b
    __shared__ float sfb[128];           // fc_b
    __shared__ float parts[16];
    __shared__ float sx0, sxl;

    const float* xr   = x + (size_t)b * LEN;
    const float4* xr4 = reinterpret_cast<const float4*>(xr);

    // ---- small weight arrays ----
    if (tid < 384) scw[tid] = conv_w[tid];
    else if (tid < 512) scb[tid - 384] = conv_b[tid - 384];
    else if (tid < 640) sfb[tid - 512] = fc_b[tid - 512];
    if (tid == 0) { sx0 = xr[0]; sxl = xr[LEN - 1]; }

    // ---- fc_w loads for G (8 threads per tap): t = tid>>3, c in [16q,16q+16) ----
    const int t = tid >> 3, q = tid & 7;
    const float4* fw4 = reinterpret_cast<const float4*>(fc_w);
    float4 fw[4];
    #pragma unroll
    for (int m = 0; m < 4; ++m) fw[m] = fw4[32 * t + 4 * q + m];

    // ---- single full-row read: sum + bf16 stage ----
    float s = 0.f;
    #pragma unroll
    for (int p = 0; p < 5; ++p) {
        const int i = tid + 1024 * p;            // float4 index into sxp
        if (i < SPAN4) {
            const int g4 = i - 32;               // x float4 index (xp shift = 128 floats)
            float4 v = make_float4(0.f, 0.f, 0.f, 0.f);
            if (g4 >= 0 && g4 < LEN / 4) v = xr4[g4];
            s += (v.x + v.y) + (v.z + v.w);
            ushort4 hv;
            hv.x = f2bf(v.x); hv.y = f2bf(v.y); hv.z = f2bf(v.z); hv.w = f2bf(v.w);
            *reinterpret_cast<ushort4*>(&sxp[4 * i]) = hv;
        }
    }

    // ---- block-wide row sum ----
    #pragma unroll
    for (int off = 32; off > 0; off >>= 1) s += __shfl_down(s, off, 64);
    if ((tid & 63) == 0) parts[tid >> 6] = s;
    __syncthreads();
    float Sb = 0.f;
    #pragma unroll
    for (int i = 0; i < 16; ++i) Sb += parts[i];

    // ---- G0,G1,G2,H partials over c in [16q, 16q+16) ----
    float g0 = 0.f, g1 = 0.f, g2 = 0.f, hh = 0.f;
    #pragma unroll
    for (int m = 0; m < 4; ++m) {
        const float fv[4] = {fw[m].x, fw[m].y, fw[m].z, fw[m].w};
        #pragma unroll
        for (int jj = 0; jj < 4; ++jj) {
            const int c = 16 * q + 4 * m + jj;
            const float f = fv[jj];
            g0 = fmaf(f, scw[3 * c + 0], g0);
            g1 = fmaf(f, scw[3 * c + 1], g1);
            g2 = fmaf(f, scb[c], hh) , hh = g2, g2 = 0.f; // placeholder avoided below
        }
    }
    // NOTE: the trick line above is wrong-prone; recompute cleanly:
    g0 = 0.f; g1 = 0.f; g2 = 0.f; hh = 0.f;
    #pragma unroll
    for (int m = 0; m < 4; ++m) {
        const float fv[4] = {fw[m].x, fw[m].y, fw[m].z, fw[m].w};
        #pragma unroll
        for (int jj = 0; jj < 4; ++jj) {
            const int c = 16 * q + 4 * m + jj;
            const float f = fv[jj];
            g0 = fmaf(f, scw[3 * c + 0], g0);
            g1 = fmaf(f, scw[3 * c + 1], g1);
            g2 = fmaf(f, scw[3 * c + 2], g2);
            hh = fmaf(f, scb[c], hh);
        }
    }
    g0 += __shfl_xor(g0, 1); g0 += __shfl_xor(g0, 2); g0 += __shfl_xor(g0, 4);
    g1 += __shfl_xor(g1, 1); g1 += __shfl_xor(g1, 2); g1 += __shfl_xor(g1, 4);
    g2 += __shfl_xor(g2, 1); g2 += __shfl_xor(g2, 2); g2 += __shfl_xor(g2, 4);
    hh += __shfl_xor(hh, 1); hh += __shfl_xor(hh, 2); hh += __shfl_xor(hh, 4);

    if (q == 0) {
        const float invL = 1.0f / (float)LEN;
        const float flt = sfb[t] + hh
            + invL * fmaf(Sb - sxl, g0, fmaf(Sb, g1, (Sb - sx0) * g2));
        fp[128 + t] = f2bf(flt);
    }
    if (q == 1) fp[t] = 0;                 // [0,128)
    if (q == 2 && t < 32) fp[256 + t] = 0; // [256,288)
    __syncthreads();

    // ---- build A fragments (shifted filter) ----
    const int l = tid & 63, w = tid >> 6;  // 16 waves
    const int n = l & 15;                  // C-col
    const int g = l >> 4;                  // k-group
    bf16x8 afrag[5];
    #pragma unroll
    for (int kb = 0; kb < 5; ++kb)
        #pragma unroll
        for (int hf = 0; hf < 2; ++hf)
            #pragma unroll
            for (int j = 0; j < 4; ++j)
                afrag[kb][hf * 4 + j] =
                    (short)fp[128 + 32 * kb + 16 * hf + 4 * g + j - n];

    // ---- MFMA FIR: wave w handles tiles T = w + 16*it (65 tiles total) ----
    float* orow = out + (size_t)b * LOUT;
    #pragma unroll
    for (int it = 0; it < 5; ++it) {
        const int T = w + 16 * it;
        if (T >= 65) break;                       // wave-uniform
        const unsigned short* bp = &sxp[T * 256 + 16 * n + 4 * g];
        f32x4 acc = {0.f, 0.f, 0.f, 0.f};
        #pragma unroll
        for (int kb = 0; kb < 5; ++kb) {
            ushort4 lo = *reinterpret_cast<const ushort4*>(bp + 32 * kb);
            ushort4 hi = *reinterpret_cast<const ushort4*>(bp + 32 * kb + 16);
            bf16x8 bfrag;
            bfrag[0] = (short)lo.x; bfrag[1] = (short)lo.y;
            bfrag[2] = (short)lo.z; bfrag[3] = (short)lo.w;
            bfrag[4] = (short)hi.x; bfrag[5] = (short)hi.y;
            bfrag[6] = (short)hi.z; bfrag[7] = (short)hi.w;
            acc = __builtin_amdgcn_mfma_f32_16x16x32_bf16(afrag[kb], bfrag, acc, 0, 0, 0);
        }
        const int t0 = 256 * T + 16 * n + 4 * g;
        if (T < 64) {
            *reinterpret_cast<f32x4*>(&orow[t0]) = acc;
        } else {
            #pragma unroll
            for (int j = 0; j < 4; ++j)
                if (t0 + j < LOUT) orow[t0 + j] = acc[j];
        }
    }
}

extern "C" void kernel_launch(void* const* d_in, const int* in_sizes, int n_in,
                              void* d_out, int out_size, void* d_ws, size_t ws_size,
                              hipStream_t stream)
{
    const float* x      = (const float*)d_in[0];
    const float* conv_w = (const float*)d_in[1];
    const float* conv_b = (const float*)d_in[2];
    const float* fc_w   = (const float*)d_in[3];
    const float* fc_b   = (const float*)d_in[4];
    float* out = (float*)d_out;

    fused_fir<<<dim3(NB), 1024, 0, stream>>>(x, conv_w, conv_b, fc_w, fc_b, out);
}